// Round 16
// baseline (137.089 us; speedup 1.0000x reference)
//
#include <hip/hip_runtime.h>
#include <hip/hip_bf16.h>
#include <stdint.h>

#define NTOK 2048
#define HDIM 1024
#define NEXP 16
#define TOPK 4
#define IR   512
#define ISH  1024
#define RSCALE 2.5f

typedef short bf16x4 __attribute__((ext_vector_type(4)));
typedef short bf16x8 __attribute__((ext_vector_type(8)));
typedef float f32x4  __attribute__((ext_vector_type(4)));

static __device__ __forceinline__ unsigned short f2bf(float f){
  union { float fv; uint32_t u; } v; v.fv = f;
  uint32_t r = v.u + 0x7fffu + ((v.u >> 16) & 1u);
  return (unsigned short)(r >> 16);
}
static __device__ __forceinline__ float bf2f(unsigned short s){
  union { uint32_t u; float f; } v; v.u = ((uint32_t)s) << 16;
  return v.f;
}
static __device__ __forceinline__ unsigned int pkbf2(float lo, float hi){
  union { __hip_bfloat162 b; unsigned int u; } cv;
  cv.b = __float22bfloat162_rn(make_float2(lo, hi));
  return cv.u;
}

static __device__ __forceinline__ void gl_lds16(const void* gp, void* lp){
  __builtin_amdgcn_global_load_lds(
      (const __attribute__((address_space(1))) unsigned int*)gp,
      (__attribute__((address_space(3))) unsigned int*)lp, 16, 0, 0);
}

// ---------- transpose+convert all weights: src[R][C] f32 -> dst[C][R] bf16 ----------
// 64x64 tiles; LDS stride 69 floats (bank-conflict-free: 69%32=5, gcd(5,32)=1);
// 16B bf16x8 output stores.
__global__ __launch_bounds__(256) void convT_all(
    const float* __restrict__ wgu, unsigned short* __restrict__ wgu_t,
    const float* __restrict__ wdn, unsigned short* __restrict__ wdn_t,
    const float* __restrict__ sgu, unsigned short* __restrict__ sgu_t,
    const float* __restrict__ sdn, unsigned short* __restrict__ sdn_t)
{
  __shared__ float t[64 * 69];
  const int tid = threadIdx.x;
  int id = blockIdx.x;
  const float* s; unsigned short* d; int R, C, rt, ct;
  if (id < 4096){                 // wgu: 16 x [1024][1024]
    int e = id >> 8, r = id & 255; rt = r >> 4; ct = r & 15;
    R = 1024; C = 1024; s = wgu + (size_t)e * 1048576; d = wgu_t + (size_t)e * 1048576;
  } else if (id < 6144){          // wdn: 16 x [512][1024]
    id -= 4096; int e = id >> 7, r = id & 127; rt = r >> 4; ct = r & 15;
    R = 512; C = 1024; s = wdn + (size_t)e * 524288; d = wdn_t + (size_t)e * 524288;
  } else if (id < 6656){          // sgu: [1024][2048]
    id -= 6144; rt = id >> 5; ct = id & 31;
    R = 1024; C = 2048; s = sgu; d = sgu_t;
  } else {                        // sdn: [1024][1024]
    id -= 6656; rt = id >> 4; ct = id & 15;
    R = 1024; C = 1024; s = sdn; d = sdn_t;
  }
  const int r0 = rt * 64, c0 = ct * 64;
  #pragma unroll
  for (int i = 0; i < 4; i++){
    int r = i * 16 + (tid >> 4);
    int c = (tid & 15) * 4;
    float4 v = *(const float4*)(s + (size_t)(r0 + r) * C + c0 + c);
    *(float4*)(t + r * 69 + c) = v;
  }
  __syncthreads();
  #pragma unroll
  for (int it = 0; it < 2; it++){
    int q = tid + it * 256;
    int c = q >> 3, rg = (q & 7) * 8;
    union { bf16x8 v; unsigned int u[4]; } pk;
    #pragma unroll
    for (int k = 0; k < 4; k++)
      pk.u[k] = pkbf2(t[(rg + 2 * k) * 69 + c], t[(rg + 2 * k + 1) * 69 + c]);
    *(bf16x8*)(d + (size_t)(c0 + c) * R + r0 + rg) = pk.v;
  }
}

// ---------------- router: logits, sigmoid, top-4, x->bf16 ----------------
__global__ __launch_bounds__(256) void router_kernel(
    const float* __restrict__ x, const float* __restrict__ gw,
    float* __restrict__ topkw, int* __restrict__ choice,
    unsigned short* __restrict__ xbf)
{
  __shared__ float sgw[NEXP][HDIM + 8];
  const int tid = threadIdx.x;
  for (int f = tid; f < HDIM * NEXP; f += 256){
    int i = f >> 4, e = f & 15;
    sgw[e][i] = gw[f];
  }
  __syncthreads();
  const int lane = tid & 63;
  const int t = blockIdx.x * 4 + (tid >> 6);

  float s[NEXP];
  #pragma unroll
  for (int e = 0; e < NEXP; e++) s[e] = 0.f;
  #pragma unroll
  for (int j = 0; j < 8; j++){
    const int off = 128 * j + lane * 2;
    float2 xv = *(const float2*)(x + (size_t)t * HDIM + off);
    ushort2 xs = { f2bf(xv.x), f2bf(xv.y) };
    *(ushort2*)(xbf + (size_t)t * HDIM + off) = xs;
    #pragma unroll
    for (int e = 0; e < NEXP; e++){
      float2 gv = *(const float2*)(&sgw[e][off]);
      s[e] += xv.x * gv.x + xv.y * gv.y;
    }
  }
  #pragma unroll
  for (int e = 0; e < NEXP; e++){
    #pragma unroll
    for (int off = 32; off; off >>= 1)
      s[e] += __shfl_xor(s[e], off);
  }
  float sc[NEXP];
  #pragma unroll
  for (int e = 0; e < NEXP; e++) sc[e] = 1.f / (1.f + __expf(-s[e]));

  unsigned mask = 0; float w[TOPK]; int id[TOPK];
  #pragma unroll
  for (int k = 0; k < TOPK; k++){
    float best = -1e30f; int bi = 0;
    #pragma unroll
    for (int e = 0; e < NEXP; e++){
      if (!((mask >> e) & 1u) && sc[e] > best){ best = sc[e]; bi = e; }
    }
    mask |= 1u << bi; id[k] = bi; w[k] = best;
  }
  float inv = 1.f / (w[0] + w[1] + w[2] + w[3]);
  if (lane == 0){
    #pragma unroll
    for (int k = 0; k < TOPK; k++){
      topkw[t * TOPK + k] = w[k] * inv;
      choice[t * TOPK + k] = id[k];
    }
  }
}

// ---------------- build per-expert lists deterministically ----------------
__global__ __launch_bounds__(256) void build_lists(
    const int* __restrict__ choice, int* __restrict__ counts, int* __restrict__ lists)
{
  const int e = blockIdx.x;
  const int tid = threadIdx.x;
  __shared__ int scnt[256];
  const int base = tid * 32;
  unsigned m = 0; int local = 0;
  #pragma unroll
  for (int i = 0; i < 32; i++){
    bool hit = (choice[base + i] == e);
    m |= (unsigned)hit << i;
    local += hit;
  }
  scnt[tid] = local;
  __syncthreads();
  int v = local;
  for (int off = 1; off < 256; off <<= 1){
    int add = (tid >= off) ? scnt[tid - off] : 0;
    __syncthreads();
    v += add; scnt[tid] = v;
    __syncthreads();
  }
  int pos = v - local;
  #pragma unroll
  for (int i = 0; i < 32; i++){
    if ((m >> i) & 1u) lists[e * NTOK + pos++] = base + i;
  }
  if (tid == 255) counts[e] = v;
}

// ---------------- merged gate_up GEMM + SiLU*mul (R8 inner loop, XCD panel pinning) ----------------
// Grid 768. L<512 routed: p=L&7 (n0=p*64, XCD=p), t=L>>3: mIdx=t&3, e=t>>2, NCH=4.
// L>=512 shared: v=L-512: p=v&15, n0=p*64 (XCD=p&7), mIdx=v>>4, NCH=16.
__global__ __launch_bounds__(256) void gu_gemm(
    const unsigned short* __restrict__ xbf, const unsigned short* __restrict__ wgu_t,
    const unsigned short* __restrict__ sgu_t,
    unsigned short* __restrict__ act_r, unsigned short* __restrict__ act_s,
    const int* __restrict__ lists, const int* __restrict__ counts)
{
  __shared__ unsigned short sA[128 * 32];
  __shared__ unsigned short sB[128 * 32];
  __shared__ int sAid[128];

  const int tid = threadIdx.x;
  const int L = blockIdx.x;
  const bool routed = (L < 512);
  int e, mIdx, n0, count, NPAIR, NCH;
  const unsigned short* Bt;
  unsigned short* act;
  if (routed){
    int p = L & 7, t = L >> 3;
    mIdx = t & 3; e = t >> 2; n0 = p * 64;
    count = counts[e]; NPAIR = IR; NCH = 4;
    Bt = wgu_t + (size_t)e * (2 * IR) * HDIM;
    act = act_r;
  } else {
    int v = L - 512;
    e = 0; n0 = (v & 15) * 64; mIdx = v >> 4;
    count = NTOK; NPAIR = ISH; NCH = 16;
    Bt = sgu_t; act = act_s;
  }

  const int wv = tid >> 6, lane = tid & 63, lr = lane & 15, g = lane >> 4;
  const int wm = wv >> 1, wn = wv & 1;

  const unsigned short* bsrc[2];
  #pragma unroll
  for (int it = 0; it < 2; it++){
    int q = tid + it * 256;
    int c = q >> 2, ko = (q & 3) * 8;
    int grp = c >> 5, within = c & 31;
    int grow = n0 + (grp >> 1) * 32 + within + ((grp & 1) ? NPAIR : 0);
    bsrc[it] = Bt + (size_t)grow * HDIM + ko;
  }

  for (int mt = mIdx; mt * 128 < count; mt += NCH){
    const int m0 = mt * 128;
    __syncthreads();
    if (tid < 128){
      int idx = m0 + tid;
      int aid;
      if (routed) aid = (idx < count) ? lists[e * NTOK + idx] : lists[e * NTOK];
      else        aid = idx;
      sAid[tid] = aid;
    }
    __syncthreads();
    const unsigned short* asrc[2];
    #pragma unroll
    for (int it = 0; it < 2; it++){
      int q = tid + it * 256;
      int r = q >> 2, ko = (q & 3) * 8;
      int aid = sAid[r];
      int tok = routed ? (aid >> 2) : aid;
      asrc[it] = xbf + (size_t)tok * HDIM + ko;
    }

    const f32x4 z4 = {0.f, 0.f, 0.f, 0.f};
    f32x4 acc[4][4];
    #pragma unroll
    for (int i = 0; i < 4; i++)
      #pragma unroll
      for (int j = 0; j < 4; j++) acc[i][j] = z4;

    for (int k0 = 0; k0 < HDIM; k0 += 32){
      #pragma unroll
      for (int it = 0; it < 2; it++){
        gl_lds16(asrc[it] + k0, sA + (tid + it * 256) * 8);
        gl_lds16(bsrc[it] + k0, sB + (tid + it * 256) * 8);
      }
      __syncthreads();
      bf16x8 af[4], bfr[4];
      #pragma unroll
      for (int i = 0; i < 4; i++){
        af[i]  = *(const bf16x8*)(sA + (wm * 64 + i * 16 + lr) * 32 + g * 8);
        bfr[i] = *(const bf16x8*)(sB + (wn * 64 + i * 16 + lr) * 32 + g * 8);
      }
      #pragma unroll
      for (int mi = 0; mi < 4; mi++)
        #pragma unroll
        for (int ni = 0; ni < 4; ni++)
          acc[mi][ni] = __builtin_amdgcn_mfma_f32_16x16x32_bf16(af[mi], bfr[ni], acc[mi][ni], 0, 0, 0);
      __syncthreads();
    }

    #pragma unroll
    for (int mi = 0; mi < 4; mi++){
      #pragma unroll
      for (int r = 0; r < 4; r++){
        int row = wm * 64 + mi * 16 + g * 4 + r;
        if (routed && m0 + row >= count) continue;
        int aid = sAid[row];
        size_t arow = (size_t)aid * NPAIR;
        #pragma unroll
        for (int ni = 0; ni < 2; ni++){
          float gv = acc[mi][ni][r];
          float uv = acc[mi][ni + 2][r];
          float a = gv / (1.f + __expf(-gv)) * uv;
          act[arow + n0 + wn * 32 + ni * 16 + lr] = f2bf(a);
        }
      }
    }
  }
}

// ---------------- merged down GEMM (R8 inner loop, XCD panel pinning) ----------------
// Grid 640. L<512 routed: p=L&7 -> n0=p*128, t=L>>3: mIdx=t&3, e=t>>2, K=512, bf16->downout.
// L>=512 shared: v=L-512 (128): p=v&7 -> n0=p*128, mIdx=v>>3, K=1024, fp32->out.
__global__ __launch_bounds__(256) void down_gemm(
    const unsigned short* __restrict__ act_r, const unsigned short* __restrict__ act_s,
    const unsigned short* __restrict__ wdn_t, const unsigned short* __restrict__ sdn_t,
    float* __restrict__ out, unsigned short* __restrict__ downout,
    const int* __restrict__ lists, const int* __restrict__ counts)
{
  __shared__ unsigned short sA[128 * 32];
  __shared__ unsigned short sB[128 * 32];
  __shared__ int sAid[128];

  const int tid = threadIdx.x;
  const int L = blockIdx.x;
  const bool routed = (L < 512);
  int e, mIdx, n0, count, K, NCH;
  const unsigned short* Bt;
  const unsigned short* Ab;
  if (routed){
    int p = L & 7, t = L >> 3;
    mIdx = t & 3; e = t >> 2; n0 = p * 128;
    count = counts[e]; K = IR; NCH = 4;
    Bt = wdn_t + (size_t)e * HDIM * IR;
    Ab = act_r;
  } else {
    int v = L - 512;
    e = 0; n0 = (v & 7) * 128; mIdx = v >> 3;
    count = NTOK; K = ISH; NCH = 16;
    Bt = sdn_t; Ab = act_s;
  }

  const int wv = tid >> 6, lane = tid & 63, lr = lane & 15, g = lane >> 4;
  const int wm = wv >> 1, wn = wv & 1;

  const unsigned short* bsrc[2];
  #pragma unroll
  for (int it = 0; it < 2; it++){
    int q = tid + it * 256;
    int c = q >> 2, ko = (q & 3) * 8;
    bsrc[it] = Bt + (size_t)(n0 + c) * K + ko;
  }

  for (int mt = mIdx; mt * 128 < count; mt += NCH){
    const int m0 = mt * 128;
    __syncthreads();
    if (tid < 128){
      int idx = m0 + tid;
      int aid;
      if (routed) aid = (idx < count) ? lists[e * NTOK + idx] : lists[e * NTOK];
      else        aid = idx;
      sAid[tid] = aid;
    }
    __syncthreads();
    const unsigned short* asrc[2];
    #pragma unroll
    for (int it = 0; it < 2; it++){
      int q = tid + it * 256;
      int r = q >> 2, ko = (q & 3) * 8;
      asrc[it] = Ab + (size_t)sAid[r] * K + ko;
    }

    const f32x4 z4 = {0.f, 0.f, 0.f, 0.f};
    f32x4 acc[4][4];
    #pragma unroll
    for (int i = 0; i < 4; i++)
      #pragma unroll
      for (int j = 0; j < 4; j++) acc[i][j] = z4;

    for (int k0 = 0; k0 < K; k0 += 32){
      #pragma unroll
      for (int it = 0; it < 2; it++){
        gl_lds16(asrc[it] + k0, sA + (tid + it * 256) * 8);
        gl_lds16(bsrc[it] + k0, sB + (tid + it * 256) * 8);
      }
      __syncthreads();
      bf16x8 af[4], bfr[4];
      #pragma unroll
      for (int i = 0; i < 4; i++){
        af[i]  = *(const bf16x8*)(sA + (wm * 64 + i * 16 + lr) * 32 + g * 8);
        bfr[i] = *(const bf16x8*)(sB + (wn * 64 + i * 16 + lr) * 32 + g * 8);
      }
      #pragma unroll
      for (int mi = 0; mi < 4; mi++)
        #pragma unroll
        for (int ni = 0; ni < 4; ni++)
          acc[mi][ni] = __builtin_amdgcn_mfma_f32_16x16x32_bf16(af[mi], bfr[ni], acc[mi][ni], 0, 0, 0);
      __syncthreads();
    }

    #pragma unroll
    for (int mi = 0; mi < 4; mi++){
      #pragma unroll
      for (int r = 0; r < 4; r++){
        int row = wm * 64 + mi * 16 + g * 4 + r;
        if (m0 + row >= count) continue;
        int aid = sAid[row];
        size_t orow = (size_t)aid * HDIM;
        if (routed){
          #pragma unroll
          for (int ni = 0; ni < 4; ni++)
            downout[orow + n0 + wn * 64 + ni * 16 + lr] = f2bf(acc[mi][ni][r]);
        } else {
          #pragma unroll
          for (int ni = 0; ni < 4; ni++)
            out[orow + n0 + wn * 64 + ni * 16 + lr] = acc[mi][ni][r];
        }
      }
    }
  }
}

// ---------------- combine: out += RSCALE * sum_k w_k * down_k ----------------
// out was fully written by down_gemm(shared) this call => deterministic RMW.
__global__ __launch_bounds__(256) void combine_kernel(
    float* __restrict__ out, const unsigned short* __restrict__ downout,
    const float* __restrict__ topkw)
{
  const int idx = blockIdx.x * 256 + threadIdx.x;
  const int t = idx >> 8;
  const int c4 = (idx & 255) * 4;
  float4 o = *(float4*)(out + (size_t)t * HDIM + c4);
  float r0 = 0.f, r1 = 0.f, r2 = 0.f, r3 = 0.f;
  #pragma unroll
  for (int k = 0; k < TOPK; k++){
    float w = topkw[t * TOPK + k];
    const ushort4 dv = *(const ushort4*)(downout + (size_t)(t * TOPK + k) * HDIM + c4);
    r0 += w * bf2f(dv.x); r1 += w * bf2f(dv.y);
    r2 += w * bf2f(dv.z); r3 += w * bf2f(dv.w);
  }
  o.x += RSCALE * r0; o.y += RSCALE * r1; o.z += RSCALE * r2; o.w += RSCALE * r3;
  *(float4*)(out + (size_t)t * HDIM + c4) = o;
}

extern "C" void kernel_launch(void* const* d_in, const int* in_sizes, int n_in,
                              void* d_out, int out_size, void* d_ws, size_t ws_size,
                              hipStream_t stream) {
  const float* x   = (const float*)d_in[0];
  const float* gw  = (const float*)d_in[1];
  const float* wgu = (const float*)d_in[2];
  const float* wdn = (const float*)d_in[3];
  const float* sgu = (const float*)d_in[4];
  const float* sdn = (const float*)d_in[5];
  float* out = (float*)d_out;

  char* ws = (char*)d_ws;
  float* topkw = (float*)(ws + 0);                                        // 32 KB
  int* choice  = (int*)(ws + 32768);                                      // 32 KB
  int* counts  = (int*)(ws + 65536);                                      // 256 B
  int* lists   = (int*)(ws + 65792);                                      // 128 KB -> 196864
  unsigned short* xbf   = (unsigned short*)(ws + 197120);                 // 4 MB
  unsigned short* wgu_t = (unsigned short*)(ws + 197120 + 4194304ull);    // 32 MB
  unsigned short* wdn_t = (unsigned short*)(ws + 197120 + 37748736ull);   // 16 MB
  unsigned short* sgu_t = (unsigned short*)(ws + 197120 + 54525952ull);   // 4 MB
  unsigned short* sdn_t = (unsigned short*)(ws + 197120 + 58720256ull);   // 2 MB
  unsigned short* act_r = (unsigned short*)(ws + 197120 + 60817408ull);   // 8 MB
  unsigned short* act_s = (unsigned short*)(ws + 197120 + 69206016ull);   // 4 MB -> ~73.6 MB total
  // downout (16 MB) aliases wgu_t: wgu_t's last read is gu_gemm, which completes
  // before down_gemm writes it (same stream); convT_all rewrites it each replay.
  unsigned short* downout = wgu_t;

  router_kernel<<<NTOK / 4, 256, 0, stream>>>(x, gw, topkw, choice, xbf);
  build_lists<<<NEXP, 256, 0, stream>>>(choice, counts, lists);
  convT_all<<<6912, 256, 0, stream>>>(wgu, wgu_t, wdn, wdn_t, sgu, sgu_t, sdn, sdn_t);

  gu_gemm<<<768, 256, 0, stream>>>(xbf, wgu_t, sgu_t, act_r, act_s, lists, counts);
  down_gemm<<<640, 256, 0, stream>>>(act_r, act_s, wdn_t, sdn_t, out, downout, lists, counts);
  combine_kernel<<<(NTOK * HDIM / 4) / 256, 256, 0, stream>>>(out, downout, topkw);
}

// Round 17
// 132.623 us; speedup vs baseline: 1.0337x; 1.0337x over previous
//
#include <hip/hip_runtime.h>
#include <hip/hip_bf16.h>
#include <stdint.h>

#define NTOK 2048
#define HDIM 1024
#define NEXP 16
#define TOPK 4
#define IR   512
#define ISH  1024
#define RSCALE 2.5f

typedef short bf16x4 __attribute__((ext_vector_type(4)));
typedef short bf16x8 __attribute__((ext_vector_type(8)));
typedef float f32x4  __attribute__((ext_vector_type(4)));

static __device__ __forceinline__ unsigned short f2bf(float f){
  union { float fv; uint32_t u; } v; v.fv = f;
  uint32_t r = v.u + 0x7fffu + ((v.u >> 16) & 1u);
  return (unsigned short)(r >> 16);
}
static __device__ __forceinline__ float bf2f(unsigned short s){
  union { uint32_t u; float f; } v; v.u = ((uint32_t)s) << 16;
  return v.f;
}
static __device__ __forceinline__ unsigned int pkbf2(float lo, float hi){
  union { __hip_bfloat162 b; unsigned int u; } cv;
  cv.b = __float22bfloat162_rn(make_float2(lo, hi));
  return cv.u;
}

static __device__ __forceinline__ void gl_lds16(const void* gp, void* lp){
  __builtin_amdgcn_global_load_lds(
      (const __attribute__((address_space(1))) unsigned int*)gp,
      (__attribute__((address_space(3))) unsigned int*)lp, 16, 0, 0);
}

// ---------------- prep: router (blocks 0..511, LDS-free) + weight transpose/convert ----------------
// convT: 64x64 tiles, LDS stride 69 (conflict-free), 16B bf16x8 stores.
__global__ __launch_bounds__(256) void prep_kernel(
    const float* __restrict__ x, const float* __restrict__ gw,
    float* __restrict__ topkw, int* __restrict__ choice,
    unsigned short* __restrict__ xbf,
    const float* __restrict__ wgu, unsigned short* __restrict__ wgu_t,
    const float* __restrict__ wdn, unsigned short* __restrict__ wdn_t,
    const float* __restrict__ sgu, unsigned short* __restrict__ sgu_t,
    const float* __restrict__ sdn, unsigned short* __restrict__ sdn_t)
{
  __shared__ float tile[64 * 69];
  const int tid = threadIdx.x;
  const int bid = blockIdx.x;

  if (bid < 512){
    // ---- router: 4 tokens/block, gw read from L2 (64 KB, fully cached) ----
    const int lane = tid & 63;
    const int t = bid * 4 + (tid >> 6);
    float s[NEXP];
    #pragma unroll
    for (int e = 0; e < NEXP; e++) s[e] = 0.f;
    #pragma unroll
    for (int j = 0; j < 8; j++){
      const int off = 128 * j + lane * 2;
      float2 xv = *(const float2*)(x + (size_t)t * HDIM + off);
      ushort2 xs = { f2bf(xv.x), f2bf(xv.y) };
      *(ushort2*)(xbf + (size_t)t * HDIM + off) = xs;
      const float4* g0 = (const float4*)(gw + (size_t)off * NEXP);
      const float4* g1 = (const float4*)(gw + (size_t)(off + 1) * NEXP);
      #pragma unroll
      for (int q = 0; q < 4; q++){
        float4 a = g0[q], b = g1[q];
        s[q * 4 + 0] += xv.x * a.x + xv.y * b.x;
        s[q * 4 + 1] += xv.x * a.y + xv.y * b.y;
        s[q * 4 + 2] += xv.x * a.z + xv.y * b.z;
        s[q * 4 + 3] += xv.x * a.w + xv.y * b.w;
      }
    }
    #pragma unroll
    for (int e = 0; e < NEXP; e++){
      #pragma unroll
      for (int off = 32; off; off >>= 1)
        s[e] += __shfl_xor(s[e], off);
    }
    float sc[NEXP];
    #pragma unroll
    for (int e = 0; e < NEXP; e++) sc[e] = 1.f / (1.f + __expf(-s[e]));
    unsigned mask = 0; float w[TOPK]; int id[TOPK];
    #pragma unroll
    for (int k = 0; k < TOPK; k++){
      float best = -1e30f; int bi = 0;
      #pragma unroll
      for (int e = 0; e < NEXP; e++){
        if (!((mask >> e) & 1u) && sc[e] > best){ best = sc[e]; bi = e; }
      }
      mask |= 1u << bi; id[k] = bi; w[k] = best;
    }
    float inv = 1.f / (w[0] + w[1] + w[2] + w[3]);
    if (lane == 0){
      #pragma unroll
      for (int k = 0; k < TOPK; k++){
        topkw[t * TOPK + k] = w[k] * inv;
        choice[t * TOPK + k] = id[k];
      }
    }
    return;
  }

  // ---- transpose+convert: src[R][C] f32 -> dst[C][R] bf16 ----
  int id = bid - 512;
  const float* s; unsigned short* d; int R, C, rt, ct;
  if (id < 4096){                 // wgu: 16 x [1024][1024]
    int e = id >> 8, r = id & 255; rt = r >> 4; ct = r & 15;
    R = 1024; C = 1024; s = wgu + (size_t)e * 1048576; d = wgu_t + (size_t)e * 1048576;
  } else if (id < 6144){          // wdn: 16 x [512][1024]
    id -= 4096; int e = id >> 7, r = id & 127; rt = r >> 4; ct = r & 15;
    R = 512; C = 1024; s = wdn + (size_t)e * 524288; d = wdn_t + (size_t)e * 524288;
  } else if (id < 6656){          // sgu: [1024][2048]
    id -= 6144; rt = id >> 5; ct = id & 31;
    R = 1024; C = 2048; s = sgu; d = sgu_t;
  } else {                        // sdn: [1024][1024]
    id -= 6656; rt = id >> 4; ct = id & 15;
    R = 1024; C = 1024; s = sdn; d = sdn_t;
  }
  const int r0 = rt * 64, c0 = ct * 64;
  #pragma unroll
  for (int i = 0; i < 4; i++){
    int r = i * 16 + (tid >> 4);
    int c = (tid & 15) * 4;
    float4 v = *(const float4*)(s + (size_t)(r0 + r) * C + c0 + c);
    *(float4*)(tile + r * 69 + c) = v;
  }
  __syncthreads();
  #pragma unroll
  for (int it = 0; it < 2; it++){
    int q = tid + it * 256;
    int c = q >> 3, rg = (q & 7) * 8;
    union { bf16x8 v; unsigned int u[4]; } pk;
    #pragma unroll
    for (int k = 0; k < 4; k++)
      pk.u[k] = pkbf2(tile[(rg + 2 * k) * 69 + c], tile[(rg + 2 * k + 1) * 69 + c]);
    *(bf16x8*)(d + (size_t)(c0 + c) * R + r0 + rg) = pk.v;
  }
}

// ---------------- build per-expert lists deterministically ----------------
__global__ __launch_bounds__(256) void build_lists(
    const int* __restrict__ choice, int* __restrict__ counts, int* __restrict__ lists)
{
  const int e = blockIdx.x;
  const int tid = threadIdx.x;
  __shared__ int scnt[256];
  const int base = tid * 32;
  unsigned m = 0; int local = 0;
  #pragma unroll
  for (int i = 0; i < 32; i++){
    bool hit = (choice[base + i] == e);
    m |= (unsigned)hit << i;
    local += hit;
  }
  scnt[tid] = local;
  __syncthreads();
  int v = local;
  for (int off = 1; off < 256; off <<= 1){
    int add = (tid >= off) ? scnt[tid - off] : 0;
    __syncthreads();
    v += add; scnt[tid] = v;
    __syncthreads();
  }
  int pos = v - local;
  #pragma unroll
  for (int i = 0; i < 32; i++){
    if ((m >> i) & 1u) lists[e * NTOK + pos++] = base + i;
  }
  if (tid == 255) counts[e] = v;
}

// ---------------- merged gate_up GEMM + SiLU*mul (BK=64 twin-buffer, XCD pinning) ----------------
// Grid 768. L<512 routed: p=L&7 (n0=p*64, XCD=p), t=L>>3: mIdx=t&3, e=t>>2, NCH=4.
// L>=512 shared: v=L-512: p=v&15, n0=p*64, mIdx=v>>4, NCH=16.
// Per 64-k step: stage both 32-halves (8 gl_lds/thread), 1 barrier pair, 32 MFMAs.
__global__ __launch_bounds__(256) void gu_gemm(
    const unsigned short* __restrict__ xbf, const unsigned short* __restrict__ wgu_t,
    const unsigned short* __restrict__ sgu_t,
    unsigned short* __restrict__ act_r, unsigned short* __restrict__ act_s,
    const int* __restrict__ lists, const int* __restrict__ counts)
{
  __shared__ unsigned short sA[2][128 * 32];
  __shared__ unsigned short sB[2][128 * 32];
  __shared__ int sAid[128];

  const int tid = threadIdx.x;
  const int L = blockIdx.x;
  const bool routed = (L < 512);
  int e, mIdx, n0, count, NPAIR, NCH;
  const unsigned short* Bt;
  unsigned short* act;
  if (routed){
    int p = L & 7, t = L >> 3;
    mIdx = t & 3; e = t >> 2; n0 = p * 64;
    count = counts[e]; NPAIR = IR; NCH = 4;
    Bt = wgu_t + (size_t)e * (2 * IR) * HDIM;
    act = act_r;
  } else {
    int v = L - 512;
    e = 0; n0 = (v & 15) * 64; mIdx = v >> 4;
    count = NTOK; NPAIR = ISH; NCH = 16;
    Bt = sgu_t; act = act_s;
  }

  const int wv = tid >> 6, lane = tid & 63, lr = lane & 15, g = lane >> 4;
  const int wm = wv >> 1, wn = wv & 1;

  const unsigned short* bsrc[2];
  #pragma unroll
  for (int it = 0; it < 2; it++){
    int q = tid + it * 256;
    int c = q >> 2, ko = (q & 3) * 8;
    int grp = c >> 5, within = c & 31;
    int grow = n0 + (grp >> 1) * 32 + within + ((grp & 1) ? NPAIR : 0);
    bsrc[it] = Bt + (size_t)grow * HDIM + ko;
  }

  for (int mt = mIdx; mt * 128 < count; mt += NCH){
    const int m0 = mt * 128;
    __syncthreads();
    if (tid < 128){
      int idx = m0 + tid;
      int aid;
      if (routed) aid = (idx < count) ? lists[e * NTOK + idx] : lists[e * NTOK];
      else        aid = idx;
      sAid[tid] = aid;
    }
    __syncthreads();
    const unsigned short* asrc[2];
    #pragma unroll
    for (int it = 0; it < 2; it++){
      int q = tid + it * 256;
      int r = q >> 2, ko = (q & 3) * 8;
      int aid = sAid[r];
      int tok = routed ? (aid >> 2) : aid;
      asrc[it] = xbf + (size_t)tok * HDIM + ko;
    }

    const f32x4 z4 = {0.f, 0.f, 0.f, 0.f};
    f32x4 acc[4][4];
    #pragma unroll
    for (int i = 0; i < 4; i++)
      #pragma unroll
      for (int j = 0; j < 4; j++) acc[i][j] = z4;

    for (int k0 = 0; k0 < HDIM; k0 += 64){
      #pragma unroll
      for (int it = 0; it < 2; it++){
        gl_lds16(asrc[it] + k0,      sA[0] + (tid + it * 256) * 8);
        gl_lds16(asrc[it] + k0 + 32, sA[1] + (tid + it * 256) * 8);
        gl_lds16(bsrc[it] + k0,      sB[0] + (tid + it * 256) * 8);
        gl_lds16(bsrc[it] + k0 + 32, sB[1] + (tid + it * 256) * 8);
      }
      __syncthreads();
      #pragma unroll
      for (int h = 0; h < 2; h++){
        bf16x8 af[4], bfr[4];
        #pragma unroll
        for (int i = 0; i < 4; i++){
          af[i]  = *(const bf16x8*)(sA[h] + (wm * 64 + i * 16 + lr) * 32 + g * 8);
          bfr[i] = *(const bf16x8*)(sB[h] + (wn * 64 + i * 16 + lr) * 32 + g * 8);
        }
        #pragma unroll
        for (int mi = 0; mi < 4; mi++)
          #pragma unroll
          for (int ni = 0; ni < 4; ni++)
            acc[mi][ni] = __builtin_amdgcn_mfma_f32_16x16x32_bf16(af[mi], bfr[ni], acc[mi][ni], 0, 0, 0);
      }
      __syncthreads();
    }

    #pragma unroll
    for (int mi = 0; mi < 4; mi++){
      #pragma unroll
      for (int r = 0; r < 4; r++){
        int row = wm * 64 + mi * 16 + g * 4 + r;
        if (routed && m0 + row >= count) continue;
        int aid = sAid[row];
        size_t arow = (size_t)aid * NPAIR;
        #pragma unroll
        for (int ni = 0; ni < 2; ni++){
          float gv = acc[mi][ni][r];
          float uv = acc[mi][ni + 2][r];
          float a = gv / (1.f + __expf(-gv)) * uv;
          act[arow + n0 + wn * 32 + ni * 16 + lr] = f2bf(a);
        }
      }
    }
  }
}

// ---------------- merged down GEMM (BK=64 twin-buffer, XCD pinning) ----------------
// Grid 640. L<512 routed: p=L&7 -> n0=p*128, t=L>>3: mIdx=t&3, e=t>>2, K=512, bf16->downout.
// L>=512 shared: v=L-512 (128): p=v&7 -> n0=p*128, mIdx=v>>3, K=1024, fp32->out.
__global__ __launch_bounds__(256) void down_gemm(
    const unsigned short* __restrict__ act_r, const unsigned short* __restrict__ act_s,
    const unsigned short* __restrict__ wdn_t, const unsigned short* __restrict__ sdn_t,
    float* __restrict__ out, unsigned short* __restrict__ downout,
    const int* __restrict__ lists, const int* __restrict__ counts)
{
  __shared__ unsigned short sA[2][128 * 32];
  __shared__ unsigned short sB[2][128 * 32];
  __shared__ int sAid[128];

  const int tid = threadIdx.x;
  const int L = blockIdx.x;
  const bool routed = (L < 512);
  int e, mIdx, n0, count, K, NCH;
  const unsigned short* Bt;
  const unsigned short* Ab;
  if (routed){
    int p = L & 7, t = L >> 3;
    mIdx = t & 3; e = t >> 2; n0 = p * 128;
    count = counts[e]; K = IR; NCH = 4;
    Bt = wdn_t + (size_t)e * HDIM * IR;
    Ab = act_r;
  } else {
    int v = L - 512;
    e = 0; n0 = (v & 7) * 128; mIdx = v >> 3;
    count = NTOK; K = ISH; NCH = 16;
    Bt = sdn_t; Ab = act_s;
  }

  const int wv = tid >> 6, lane = tid & 63, lr = lane & 15, g = lane >> 4;
  const int wm = wv >> 1, wn = wv & 1;

  const unsigned short* bsrc[2];
  #pragma unroll
  for (int it = 0; it < 2; it++){
    int q = tid + it * 256;
    int c = q >> 2, ko = (q & 3) * 8;
    bsrc[it] = Bt + (size_t)(n0 + c) * K + ko;
  }

  for (int mt = mIdx; mt * 128 < count; mt += NCH){
    const int m0 = mt * 128;
    __syncthreads();
    if (tid < 128){
      int idx = m0 + tid;
      int aid;
      if (routed) aid = (idx < count) ? lists[e * NTOK + idx] : lists[e * NTOK];
      else        aid = idx;
      sAid[tid] = aid;
    }
    __syncthreads();
    const unsigned short* asrc[2];
    #pragma unroll
    for (int it = 0; it < 2; it++){
      int q = tid + it * 256;
      int r = q >> 2, ko = (q & 3) * 8;
      asrc[it] = Ab + (size_t)sAid[r] * K + ko;
    }

    const f32x4 z4 = {0.f, 0.f, 0.f, 0.f};
    f32x4 acc[4][4];
    #pragma unroll
    for (int i = 0; i < 4; i++)
      #pragma unroll
      for (int j = 0; j < 4; j++) acc[i][j] = z4;

    for (int k0 = 0; k0 < K; k0 += 64){
      #pragma unroll
      for (int it = 0; it < 2; it++){
        gl_lds16(asrc[it] + k0,      sA[0] + (tid + it * 256) * 8);
        gl_lds16(asrc[it] + k0 + 32, sA[1] + (tid + it * 256) * 8);
        gl_lds16(bsrc[it] + k0,      sB[0] + (tid + it * 256) * 8);
        gl_lds16(bsrc[it] + k0 + 32, sB[1] + (tid + it * 256) * 8);
      }
      __syncthreads();
      #pragma unroll
      for (int h = 0; h < 2; h++){
        bf16x8 af[4], bfr[4];
        #pragma unroll
        for (int i = 0; i < 4; i++){
          af[i]  = *(const bf16x8*)(sA[h] + (wm * 64 + i * 16 + lr) * 32 + g * 8);
          bfr[i] = *(const bf16x8*)(sB[h] + (wn * 64 + i * 16 + lr) * 32 + g * 8);
        }
        #pragma unroll
        for (int mi = 0; mi < 4; mi++)
          #pragma unroll
          for (int ni = 0; ni < 4; ni++)
            acc[mi][ni] = __builtin_amdgcn_mfma_f32_16x16x32_bf16(af[mi], bfr[ni], acc[mi][ni], 0, 0, 0);
      }
      __syncthreads();
    }

    #pragma unroll
    for (int mi = 0; mi < 4; mi++){
      #pragma unroll
      for (int r = 0; r < 4; r++){
        int row = wm * 64 + mi * 16 + g * 4 + r;
        if (m0 + row >= count) continue;
        int aid = sAid[row];
        size_t orow = (size_t)aid * HDIM;
        if (routed){
          #pragma unroll
          for (int ni = 0; ni < 4; ni++)
            downout[orow + n0 + wn * 64 + ni * 16 + lr] = f2bf(acc[mi][ni][r]);
        } else {
          #pragma unroll
          for (int ni = 0; ni < 4; ni++)
            out[orow + n0 + wn * 64 + ni * 16 + lr] = acc[mi][ni][r];
        }
      }
    }
  }
}

// ---------------- combine: out += RSCALE * sum_k w_k * down_k ----------------
__global__ __launch_bounds__(256) void combine_kernel(
    float* __restrict__ out, const unsigned short* __restrict__ downout,
    const float* __restrict__ topkw)
{
  const int idx = blockIdx.x * 256 + threadIdx.x;
  const int t = idx >> 8;
  const int c4 = (idx & 255) * 4;
  float4 o = *(float4*)(out + (size_t)t * HDIM + c4);
  float r0 = 0.f, r1 = 0.f, r2 = 0.f, r3 = 0.f;
  #pragma unroll
  for (int k = 0; k < TOPK; k++){
    float w = topkw[t * TOPK + k];
    const ushort4 dv = *(const ushort4*)(downout + (size_t)(t * TOPK + k) * HDIM + c4);
    r0 += w * bf2f(dv.x); r1 += w * bf2f(dv.y);
    r2 += w * bf2f(dv.z); r3 += w * bf2f(dv.w);
  }
  o.x += RSCALE * r0; o.y += RSCALE * r1; o.z += RSCALE * r2; o.w += RSCALE * r3;
  *(float4*)(out + (size_t)t * HDIM + c4) = o;
}

extern "C" void kernel_launch(void* const* d_in, const int* in_sizes, int n_in,
                              void* d_out, int out_size, void* d_ws, size_t ws_size,
                              hipStream_t stream) {
  const float* x   = (const float*)d_in[0];
  const float* gw  = (const float*)d_in[1];
  const float* wgu = (const float*)d_in[2];
  const float* wdn = (const float*)d_in[3];
  const float* sgu = (const float*)d_in[4];
  const float* sdn = (const float*)d_in[5];
  float* out = (float*)d_out;

  char* ws = (char*)d_ws;
  float* topkw = (float*)(ws + 0);                                        // 32 KB
  int* choice  = (int*)(ws + 32768);                                      // 32 KB
  int* counts  = (int*)(ws + 65536);                                      // 256 B
  int* lists   = (int*)(ws + 65792);                                      // 128 KB -> 196864
  unsigned short* xbf   = (unsigned short*)(ws + 197120);                 // 4 MB
  unsigned short* wgu_t = (unsigned short*)(ws + 197120 + 4194304ull);    // 32 MB
  unsigned short* wdn_t = (unsigned short*)(ws + 197120 + 37748736ull);   // 16 MB
  unsigned short* sgu_t = (unsigned short*)(ws + 197120 + 54525952ull);   // 4 MB
  unsigned short* sdn_t = (unsigned short*)(ws + 197120 + 58720256ull);   // 2 MB
  unsigned short* act_r = (unsigned short*)(ws + 197120 + 60817408ull);   // 8 MB
  unsigned short* act_s = (unsigned short*)(ws + 197120 + 69206016ull);   // 4 MB -> ~73.6 MB total
  // downout (16 MB) aliases wgu_t: wgu_t's last read is gu_gemm, which completes
  // before down_gemm writes it (same stream); prep_kernel rewrites it each replay.
  unsigned short* downout = wgu_t;

  prep_kernel<<<512 + 6912, 256, 0, stream>>>(x, gw, topkw, choice, xbf,
                                              wgu, wgu_t, wdn, wdn_t,
                                              sgu, sgu_t, sdn, sdn_t);
  build_lists<<<NEXP, 256, 0, stream>>>(choice, counts, lists);
  gu_gemm<<<768, 256, 0, stream>>>(xbf, wgu_t, sgu_t, act_r, act_s, lists, counts);
  down_gemm<<<640, 256, 0, stream>>>(act_r, act_s, wdn_t, sdn_t, out, downout, lists, counts);
  combine_kernel<<<(NTOK * HDIM / 4) / 256, 256, 0, stream>>>(out, downout, topkw);
}